// Round 7
// baseline (266.604 us; speedup 1.0000x reference)
//
#include <hip/hip_runtime.h>
#include <hip/hip_cooperative_groups.h>
#include <math.h>

namespace cg = cooperative_groups;

#define BATCH 32
#define NPTS 1024
#define DIM 64
#define EPS_DIV 1e-8f
#define EPS_NORM 1e-8f
#define BN (BATCH * NPTS)
#define OFFQ ((size_t)BATCH * NPTS * DIM)

typedef __attribute__((ext_vector_type(8))) short short8v;
typedef __attribute__((ext_vector_type(4))) float f32x4;

static __device__ __forceinline__ unsigned short f2bf(float f) {
    unsigned u = __float_as_uint(f);
    return (unsigned short)((u + 0x7FFFu + ((u >> 16) & 1u)) >> 16);
}
static __device__ __forceinline__ float bf2f(unsigned short h) {
    return __uint_as_float(((unsigned)h) << 16);
}
static __device__ __forceinline__ float fsqrt(float x) {
#if __has_builtin(__builtin_amdgcn_sqrtf)
    return __builtin_amdgcn_sqrtf(x);
#else
    return sqrtf(x);
#endif
}

// One cooperative kernel: 256 blocks (1/CU) x 512 threads (8 waves).
// Phase A: normalize-prep; B: colsum -> v; C: loss rows -> parts; D: final.
__global__ __launch_bounds__(512, 2) void k_all(
    const float* __restrict__ p, const float* __restrict__ q,
    unsigned short* __restrict__ xb, float* __restrict__ rr,
    float* __restrict__ scpart, float* __restrict__ v,
    float* __restrict__ svpart, float* __restrict__ parts,
    float* __restrict__ out) {
    cg::grid_group grid = cg::this_grid();
    int t = threadIdx.x;
    int blk = blockIdx.x;
    int lane = t & 63, w = t >> 6;
    int lr = lane & 15, lk = lane >> 4;
    __shared__ float sm[512];
    __shared__ float cs[8][64];
    __shared__ float svs[NPTS];
    __shared__ float a1s[8][64], a2s[8][64];

    // ================= phase A: prep (blk -> sel,b,chunk) =================
    {
        int sel = blk >> 7, rem = blk & 127;
        int b = rem >> 2, chunk = rem & 3;          // 256-row chunk
        const float* src = (sel ? q : p) + ((size_t)b * NPTS + chunk * 256) * DIM;
        unsigned short* dst = xb + (sel ? OFFQ : 0)
                                 + ((size_t)b * NPTS + chunk * 256) * DIM;
        float* rrb = rr + sel * BN + b * NPTS + chunk * 256;
        float s = 0.f;
        #pragma unroll
        for (int it = 0; it < 8; it++) {
            int idx = it * 512 + t;                  // float4 unit; 16 per row
            float4 vv = ((const float4*)src)[idx];
            s += vv.x + vv.y + vv.z + vv.w;
            unsigned short h0 = f2bf(vv.x), h1 = f2bf(vv.y),
                           h2 = f2bf(vv.z), h3 = f2bf(vv.w);
            float r0 = bf2f(h0), r1 = bf2f(h1), r2 = bf2f(h2), r3 = bf2f(h3);
            float ss = r0 * r0 + r1 * r1 + r2 * r2 + r3 * r3;
            ushort4 o; o.x = h0; o.y = h1; o.z = h2; o.w = h3;
            ((ushort4*)dst)[idx] = o;
            ss += __shfl_xor(ss, 1);
            ss += __shfl_xor(ss, 2);
            ss += __shfl_xor(ss, 4);
            ss += __shfl_xor(ss, 8);
            if ((t & 15) == 0) rrb[idx >> 4] = ss;
        }
        sm[t] = s;
        __syncthreads();
        for (int st = 256; st > 0; st >>= 1) {
            if (t < st) sm[t] += sm[t + st];
            __syncthreads();
        }
        if (t == 0) scpart[blk] = sm[0];             // [sel][b][chunk]
    }
    __threadfence();
    grid.sync();

    // ================= phase B: colsum -> v (2 col-chunks/block) ==========
    {
        int b = blk >> 3;
        float sps = 0.f, sqs = 0.f;
        #pragma unroll
        for (int c = 0; c < 4; c++) {
            sps += scpart[b * 4 + c];
            sqs += scpart[128 + b * 4 + c];
        }
        float sp = 1.0f / (sps + EPS_NORM), sq = 1.0f / (sqs + EPS_NORM);
        float sp2 = sp * sp, sq2 = sq * sq, spq2 = 2.f * sp * sq;
        const unsigned short* xbase = xb + (size_t)b * NPTS * DIM;
        const float* rrp = rr + b * NPTS;
        const float* rrq = rr + BN + b * NPTS;
        #pragma unroll
        for (int rep = 0; rep < 2; rep++) {
            __syncthreads();                          // cs reuse guard
            int jc = (blk & 7) * 2 + rep;
            int j0 = jc * 64;
            const unsigned short* ybase = xb + OFFQ + ((size_t)b * NPTS + j0) * DIM;
            short8v bn[2][4];
            #pragma unroll
            for (int ks = 0; ks < 2; ks++)
                #pragma unroll
                for (int n = 0; n < 4; n++)
                    bn[ks][n] = *(const short8v*)(ybase + (size_t)(n * 16 + lr) * DIM
                                                  + ks * 32 + lk * 8);
            float yr[4];
            #pragma unroll
            for (int n = 0; n < 4; n++) yr[n] = sq2 * rrq[j0 + n * 16 + lr];
            float csn[4] = {0.f, 0.f, 0.f, 0.f};
            #pragma unroll
            for (int it = 0; it < 2; it++) {
                int ib = w * 128 + it * 64;
                f32x4 acc[4][4];
                #pragma unroll
                for (int m = 0; m < 4; m++)
                    #pragma unroll
                    for (int n = 0; n < 4; n++) acc[m][n] = (f32x4){0.f, 0.f, 0.f, 0.f};
                #pragma unroll
                for (int ks = 0; ks < 2; ks++) {
                    short8v am[4];
                    #pragma unroll
                    for (int m = 0; m < 4; m++)
                        am[m] = *(const short8v*)(xbase + (size_t)(ib + m * 16 + lr) * DIM
                                                  + ks * 32 + lk * 8);
                    #pragma unroll
                    for (int m = 0; m < 4; m++)
                        #pragma unroll
                        for (int n = 0; n < 4; n++)
                            acc[m][n] = __builtin_amdgcn_mfma_f32_16x16x32_bf16(
                                am[m], bn[ks][n], acc[m][n], 0, 0, 0);
                }
                #pragma unroll
                for (int m = 0; m < 4; m++) {
                    float4 xr = *(const float4*)(rrp + ib + m * 16 + lk * 4);
                    float xs[4] = {xr.x * sp2, xr.y * sp2, xr.z * sp2, xr.w * sp2};
                    #pragma unroll
                    for (int n = 0; n < 4; n++)
                        #pragma unroll
                        for (int r = 0; r < 4; r++) {
                            float sqd = fmaxf(xs[r] + yr[n] - spq2 * acc[m][n][r], 0.f);
                            csn[n] += fsqrt(sqd);
                        }
                }
            }
            #pragma unroll
            for (int n = 0; n < 4; n++) {
                csn[n] += __shfl_xor(csn[n], 16);
                csn[n] += __shfl_xor(csn[n], 32);
            }
            if (lk == 0) {
                #pragma unroll
                for (int n = 0; n < 4; n++) cs[w][n * 16 + lr] = csn[n];
            }
            __syncthreads();
            if (t < 64) {
                float s = 0.f;
                #pragma unroll
                for (int ww = 0; ww < 8; ww++) s += cs[ww][t];
                float vj = 1.0f / (1.0f - s * (10.0f / NPTS) + EPS_DIV);
                v[b * NPTS + j0 + t] = vj;
                float svv = vj;
                #pragma unroll
                for (int st = 1; st < 64; st <<= 1) svv += __shfl_xor(svv, st);
                if (t == 0) svpart[b * 16 + jc] = svv;
            }
        }
    }
    __threadfence();
    grid.sync();

    // ================= phase C: loss rows -> parts (2 row-chunks/block) ===
    {
        int b = blk >> 3;
        if (t < 256) ((float4*)svs)[t] = ((const float4*)(v + (size_t)b * NPTS))[t];
        float sV = 0.f;
        #pragma unroll
        for (int k = 0; k < 16; k++) sV += svpart[b * 16 + k];
        float sps = 0.f, sqs = 0.f;
        #pragma unroll
        for (int c = 0; c < 4; c++) {
            sps += scpart[b * 4 + c];
            sqs += scpart[128 + b * 4 + c];
        }
        float sp = 1.0f / (sps + EPS_NORM), sq = 1.0f / (sqs + EPS_NORM);
        float sp2 = sp * sp, sq2 = sq * sq, spq2 = 2.f * sp * sq;
        const unsigned short* ybase = xb + OFFQ + (size_t)b * NPTS * DIM;
        const float* rrq = rr + BN + b * NPTS;
        #pragma unroll
        for (int rep = 0; rep < 2; rep++) {
            __syncthreads();                          // svs ready / a1s reuse
            int ic = (blk & 7) * 2 + rep;
            int i0 = ic * 64;
            const unsigned short* xbase = xb + ((size_t)b * NPTS + i0) * DIM;
            short8v am[2][4];
            #pragma unroll
            for (int ks = 0; ks < 2; ks++)
                #pragma unroll
                for (int m = 0; m < 4; m++)
                    am[ks][m] = *(const short8v*)(xbase + (size_t)(m * 16 + lr) * DIM
                                                  + ks * 32 + lk * 8);
            float xs[4][4];
            #pragma unroll
            for (int m = 0; m < 4; m++) {
                float4 xr = *(const float4*)(rr + b * NPTS + i0 + m * 16 + lk * 4);
                xs[m][0] = xr.x * sp2; xs[m][1] = xr.y * sp2;
                xs[m][2] = xr.z * sp2; xs[m][3] = xr.w * sp2;
            }
            float a1[4][4] = {}, a2[4][4] = {};
            #pragma unroll
            for (int it = 0; it < 2; it++) {
                int jb = w * 128 + it * 64;
                f32x4 acc[4][4];
                #pragma unroll
                for (int m = 0; m < 4; m++)
                    #pragma unroll
                    for (int n = 0; n < 4; n++) acc[m][n] = (f32x4){0.f, 0.f, 0.f, 0.f};
                #pragma unroll
                for (int ks = 0; ks < 2; ks++) {
                    short8v bnf[4];
                    #pragma unroll
                    for (int n = 0; n < 4; n++)
                        bnf[n] = *(const short8v*)(ybase + (size_t)(jb + n * 16 + lr) * DIM
                                                   + ks * 32 + lk * 8);
                    #pragma unroll
                    for (int m = 0; m < 4; m++)
                        #pragma unroll
                        for (int n = 0; n < 4; n++)
                            acc[m][n] = __builtin_amdgcn_mfma_f32_16x16x32_bf16(
                                am[ks][m], bnf[n], acc[m][n], 0, 0, 0);
                }
                float yr[4], vjn[4];
                #pragma unroll
                for (int n = 0; n < 4; n++) {
                    yr[n] = sq2 * rrq[jb + n * 16 + lr];
                    vjn[n] = svs[jb + n * 16 + lr];
                }
                #pragma unroll
                for (int m = 0; m < 4; m++)
                    #pragma unroll
                    for (int n = 0; n < 4; n++)
                        #pragma unroll
                        for (int r = 0; r < 4; r++) {
                            float sqd = fmaxf(xs[m][r] + yr[n] - spq2 * acc[m][n][r], 0.f);
                            float rt = fsqrt(sqd);
                            float tv = rt * vjn[n];
                            a1[m][r] += tv;
                            float g = fmaf(-10.0f, rt, 1.0f);
                            a2[m][r] = fmaf(tv, g, a2[m][r]);
                        }
            }
            #pragma unroll
            for (int m = 0; m < 4; m++)
                #pragma unroll
                for (int r = 0; r < 4; r++) {
                    #pragma unroll
                    for (int st = 1; st < 16; st <<= 1) {
                        a1[m][r] += __shfl_xor(a1[m][r], st);
                        a2[m][r] += __shfl_xor(a2[m][r], st);
                    }
                }
            if (lr == 0) {
                #pragma unroll
                for (int m = 0; m < 4; m++)
                    #pragma unroll
                    for (int r = 0; r < 4; r++) {
                        a1s[w][m * 16 + lk * 4 + r] = a1[m][r];
                        a2s[w][m * 16 + lk * 4 + r] = a2[m][r];
                    }
            }
            __syncthreads();
            if (t < 64) {
                float A1 = 0.f, A2 = 0.f;
                #pragma unroll
                for (int ww = 0; ww < 8; ww++) {
                    A1 += a1s[ww][t];
                    A2 += a2s[ww][t];
                }
                float u = 1.0f / (sV - 10.0f * A1 + EPS_DIV);
                float lp = u * A2;
                #pragma unroll
                for (int st = 1; st < 64; st <<= 1) lp += __shfl_xor(lp, st);
                if (t == 0) parts[b * 16 + ic] = lp;
            }
        }
    }
    __threadfence();
    grid.sync();

    // ================= phase D: final reduce (block 0) ====================
    if (blk == 0) {
        float a = (t < 256) ? (parts[t] + parts[t + 256]) : 0.f;
        sm[t] = a;
        __syncthreads();
        for (int st = 256; st > 0; st >>= 1) {
            if (t < st) sm[t] += sm[t + st];
            __syncthreads();
        }
        if (t == 0) out[0] = sm[0] / (float)BATCH;
    }
}

extern "C" void kernel_launch(void* const* d_in, const int* in_sizes, int n_in,
                              void* d_out, int out_size, void* d_ws, size_t ws_size,
                              hipStream_t stream) {
    const float* pred   = (const float*)d_in[0];
    const float* target = (const float*)d_in[1];
    float* out = (float*)d_out;

    unsigned short* xb = (unsigned short*)d_ws;                   // 8 MB bf16
    float* fs = (float*)(xb + 2 * OFFQ);
    float* rr     = fs;                                           // 2*BN
    float* v      = rr + 2 * BN;                                  // BN
    float* scpart = v + BN;                                       // 256
    float* svpart = scpart + 256;                                 // 512
    float* parts  = svpart + 512;                                 // 512

    void* args[] = {(void*)&pred, (void*)&target, (void*)&xb, (void*)&rr,
                    (void*)&scpart, (void*)&v, (void*)&svpart, (void*)&parts,
                    (void*)&out};
    hipLaunchCooperativeKernel((const void*)k_all, dim3(256), dim3(512),
                               args, 0, stream);
}